// Round 4
// baseline (26.020 us; speedup 1.0000x reference)
//
#include <hip/hip_runtime.h>

// Problem constants (from reference)
#define BB 2
#define LL 1024
#define KK 30
#define NCH 416                // 16 positional + 16 Dnbr RBF + 24*16 pair RBF
#define PER_POS (KK * NCH)     // 12480 floats per position
#define RBF4 3000              // RBF float4 per position (30 * 100)
#define POS4 120               // positional float4 per position (30 * 4)

// _PAIRS from reference: (ia, ib) per pair slot
__device__ __constant__ unsigned char PAIR_A[24] =
    {0,2,3,4,1,1,1,1,0,0,0,4,4,3,0,2,3,4,2,3,4,2,3,2};
__device__ __constant__ unsigned char PAIR_B[24] =
    {0,2,3,4,0,2,3,4,2,3,4,2,3,2,1,1,1,1,0,0,0,4,4,3};

// Build N,Ca,C,O,Cb (15 floats) from the packed 12-float X row (3x float4)
__device__ __forceinline__ void build_atoms(float* ap, float4 x0, float4 x1, float4 x2)
{
    // N=(x0.x,y,z) Ca=(x0.w,x1.x,x1.y) C=(x1.z,x1.w,x2.x) O=(x2.y,z,w)
    const float bx = x0.w - x0.x, by = x1.x - x0.y, bz = x1.y - x0.z; // Ca-N
    const float cx = x1.z - x0.w, cy = x1.w - x1.x, cz = x2.x - x1.y; // C-Ca
    const float ax = by * cz - bz * cy;
    const float ay = bz * cx - bx * cz;
    const float az = bx * cy - by * cx;
    const float ka = -0.58273431f, kb = 0.56802827f, kc = -0.54067466f;
    ap[0]  = x0.x; ap[1]  = x0.y; ap[2]  = x0.z;     // N
    ap[3]  = x0.w; ap[4]  = x1.x; ap[5]  = x1.y;     // Ca
    ap[6]  = x1.z; ap[7]  = x1.w; ap[8]  = x2.x;     // C
    ap[9]  = x2.y; ap[10] = x2.z; ap[11] = x2.w;     // O
    ap[12] = ka * ax + kb * bx + kc * cx + x0.w;     // Cb
    ap[13] = ka * ay + kb * by + kc * cy + x1.x;
    ap[14] = ka * az + kb * bz + kc * cz + x1.y;
}

// ---------------------------------------------------------------------------
// One block = 2 consecutive positions (same batch row). 256 threads.
// All global loads issued up front; 2 barriers; then one uninterrupted,
// divergence-free write burst of ~24 float4 iterations (97.5 KB contiguous).
// ---------------------------------------------------------------------------
__global__ __launch_bounds__(256)
void feat_fused2(const float* __restrict__ X, const int* __restrict__ chainG,
                 const int* __restrict__ E_idx, const float* __restrict__ D_neighbors,
                 const float* __restrict__ W_pos, const float* __restrict__ b_pos,
                 float* __restrict__ out)
{
    __shared__ float Wst[16 * 66];     // W_pos with b_pos folded in
    __shared__ int   schain[LL];       // whole chain row for this batch
    __shared__ float latm[2][16];      // own atoms per position
    __shared__ float natm[2][KK][16];  // neighbor atoms per position
    __shared__ float pd[2][KK][26];    // scaled dists: [g][k][0]=Dnbr, [g][k][1+p]
    __shared__ int   dd[2][KK];        // positional bucket 0..65
    __shared__ int   iaib[24];
    __shared__ int   wmask[4];

    const int tid = threadIdx.x;
    const int p0  = blockIdx.x * 2;    // global position (b*L + l), even
    const int p1  = p0 + 1;
    const int l0  = p0 & (LL - 1);
    const int l1  = l0 + 1;
    const int rowbase = p0 - l0;

    // ---- stage chain row (int4) + presence mask ---------------------------
    const int4 cvv = reinterpret_cast<const int4*>(chainG + rowbase)[tid];
    reinterpret_cast<int4*>(schain)[tid] = cvv;
    int pm = (1 << cvv.x) | (1 << cvv.y) | (1 << cvv.z) | (1 << cvv.w);
    #pragma unroll
    for (int off = 32; off >= 1; off >>= 1) pm |= __shfl_xor(pm, off, 64);
    if ((tid & 63) == 0) wmask[tid >> 6] = pm;

    // ---- stage W with bias folded ----------------------------------------
    for (int i = tid; i < 16 * 66; i += 256) Wst[i] = W_pos[i] + b_pos[i / 66];
    if (tid < 24) iaib[tid] = ((int)(3 * PAIR_A[tid]) << 8) | (int)(3 * PAIR_B[tid]);

    // ---- issue all gathers for BOTH positions ----------------------------
    int jj0 = 0, jj1 = 0;
    if (tid < KK) {
        jj0 = E_idx[p0 * KK + tid];
        jj1 = E_idx[p1 * KK + tid];
        pd[0][tid][0] = D_neighbors[p0 * KK + tid] * 0.8f;
        pd[1][tid][0] = D_neighbors[p1 * KK + tid] * 0.8f;
    }
    if (tid <= KK) {
        const int j0 = (tid < KK) ? (rowbase + jj0) : p0;  // lane 30 = own row
        const int j1 = (tid < KK) ? (rowbase + jj1) : p1;
        const float4* q0 = reinterpret_cast<const float4*>(X + (size_t)j0 * 12);
        const float4* q1 = reinterpret_cast<const float4*>(X + (size_t)j1 * 12);
        const float4 a0 = q0[0], a1 = q0[1], a2 = q0[2];
        const float4 b0 = q1[0], b1 = q1[1], b2 = q1[2];
        build_atoms((tid < KK) ? &natm[0][tid][0] : &latm[0][0], a0, a1, a2);
        build_atoms((tid < KK) ? &natm[1][tid][0] : &latm[1][0], b0, b1, b2);
    }
    __syncthreads();   // barrier A — everything staged

    // ---- positional buckets (popcount residue-index math) ----------------
    if (tid < KK) {
        const int mask  = wmask[0] | wmask[1] | wmask[2] | wmask[3];
        const int npres = __popc(mask);
        {
            const int chl = schain[l0], chj = schain[jj0];
            const int cl1 = __popc(mask & ((2 << chl) - 1));
            const int cj1 = __popc(mask & ((2 << chj) - 1));
            const int rl = (cl1 < npres) ? (100 * (cl1 - 1) + l0)  : -100;
            const int rj = (cj1 < npres) ? (100 * (cj1 - 1) + jj0) : -100;
            int off = rl - rj + 32;
            off = off < 0 ? 0 : (off > 64 ? 64 : off);
            dd[0][tid] = (chl == chj) ? off : 65;
        }
        {
            const int chl = schain[l1], chj = schain[jj1];
            const int cl1 = __popc(mask & ((2 << chl) - 1));
            const int cj1 = __popc(mask & ((2 << chj) - 1));
            const int rl = (cl1 < npres) ? (100 * (cl1 - 1) + l1)  : -100;
            const int rj = (cj1 < npres) ? (100 * (cj1 - 1) + jj1) : -100;
            int off = rl - rj + 32;
            off = off < 0 ? 0 : (off > 64 ? 64 : off);
            dd[1][tid] = (chl == chj) ? off : 65;
        }
    }

    // ---- pair distances, both positions (1440 items) ---------------------
    for (int i = tid; i < 2 * KK * 24; i += 256) {
        const int g   = (i >= KK * 24);
        const int rem = i - g * (KK * 24);
        const int k   = rem / 24;
        const int p   = rem - k * 24;
        const int pk  = iaib[p];
        const int ao  = pk >> 8;
        const int bo  = pk & 255;
        const float dx = latm[g][ao]     - natm[g][k][bo];
        const float dy = latm[g][ao + 1] - natm[g][k][bo + 1];
        const float dz = latm[g][ao + 2] - natm[g][k][bo + 2];
        const float D  = sqrtf(dx * dx + dy * dy + dz * dz + 1e-6f);
        pd[g][k][1 + p] = D * 0.8f;
    }
    __syncthreads();   // barrier B — pd/dd ready

    // ---- write burst ------------------------------------------------------
    float* outp0 = out + (size_t)p0 * PER_POS;
    float* outp1 = outp0 + PER_POS;

    // positional channels: 240 float4, uniform, one iteration
    if (tid < 2 * POS4) {
        const int g   = (tid >= POS4);
        const int rem = tid - g * POS4;
        const int k   = rem >> 2;
        const int c0  = (rem & 3) * 4;
        const int d   = dd[g][tid >> 2 & 31];  // placeholder avoided below
        (void)d;
        const int dv  = dd[g][k];
        float4 v;
        v.x = Wst[(c0 + 0) * 66 + dv];
        v.y = Wst[(c0 + 1) * 66 + dv];
        v.z = Wst[(c0 + 2) * 66 + dv];
        v.w = Wst[(c0 + 3) * 66 + dv];
        float* op = g ? outp1 : outp0;
        *reinterpret_cast<float4*>(op + k * NCH + c0) = v;
    }

    // RBF channels: two uniform loops of 3000 float4 each
    const float MU0    = 1.6f;                  // 0.8 * 2.0
    const float MUSTEP = 1.0666666666666667f;   // 0.8 * (20/15)
    const float NLOG2E = -1.44269504088896f;

    #pragma unroll 1
    for (int i4 = tid; i4 < RBF4; i4 += 256) {
        const int k    = i4 / 100;
        const int rem4 = i4 - k * 100;
        const int q    = rem4 >> 2;
        const int m0   = (rem4 & 3) << 2;
        const float D8 = pd[0][k][q];
        const float mu = MU0 + (float)m0 * MUSTEP;
        const float t0 = D8 - mu;
        const float t1 = D8 - (mu + MUSTEP);
        const float t2 = D8 - (mu + 2.0f * MUSTEP);
        const float t3 = D8 - (mu + 3.0f * MUSTEP);
        float4 v;
        v.x = __builtin_amdgcn_exp2f(t0 * t0 * NLOG2E);
        v.y = __builtin_amdgcn_exp2f(t1 * t1 * NLOG2E);
        v.z = __builtin_amdgcn_exp2f(t2 * t2 * NLOG2E);
        v.w = __builtin_amdgcn_exp2f(t3 * t3 * NLOG2E);
        *reinterpret_cast<float4*>(outp0 + k * NCH + 16 + rem4 * 4) = v;
    }
    #pragma unroll 1
    for (int i4 = tid; i4 < RBF4; i4 += 256) {
        const int k    = i4 / 100;
        const int rem4 = i4 - k * 100;
        const int q    = rem4 >> 2;
        const int m0   = (rem4 & 3) << 2;
        const float D8 = pd[1][k][q];
        const float mu = MU0 + (float)m0 * MUSTEP;
        const float t0 = D8 - mu;
        const float t1 = D8 - (mu + MUSTEP);
        const float t2 = D8 - (mu + 2.0f * MUSTEP);
        const float t3 = D8 - (mu + 3.0f * MUSTEP);
        float4 v;
        v.x = __builtin_amdgcn_exp2f(t0 * t0 * NLOG2E);
        v.y = __builtin_amdgcn_exp2f(t1 * t1 * NLOG2E);
        v.z = __builtin_amdgcn_exp2f(t2 * t2 * NLOG2E);
        v.w = __builtin_amdgcn_exp2f(t3 * t3 * NLOG2E);
        *reinterpret_cast<float4*>(outp1 + k * NCH + 16 + rem4 * 4) = v;
    }
}

// ---------------------------------------------------------------------------
extern "C" void kernel_launch(void* const* d_in, const int* in_sizes, int n_in,
                              void* d_out, int out_size, void* d_ws, size_t ws_size,
                              hipStream_t stream)
{
    const float* X           = (const float*)d_in[0];
    const int*   chain_idx   = (const int*)  d_in[1];
    // d_in[2] = mask: unused by the reference forward
    const int*   E_idx       = (const int*)  d_in[3];
    const float* D_neighbors = (const float*)d_in[4];
    const float* W_pos       = (const float*)d_in[5];
    const float* b_pos       = (const float*)d_in[6];
    float* out = (float*)d_out;

    feat_fused2<<<(BB * LL) / 2, 256, 0, stream>>>(X, chain_idx, E_idx,
                                                   D_neighbors, W_pos, b_pos, out);
}